// Round 14
// baseline (286.850 us; speedup 1.0000x reference)
//
#include <hip/hip_runtime.h>

#define DD 2048
#define SS 8192
#define BB 8
#define TWO_D 4096
#define LN_EPS 1e-5f
#define NCHAIN 256              // chain blocks (8 output cols each)
#define S1     6800             // copy rows per k1t launch
#define NCOPY1 850              // S1/8
#define S2     2565             // copy rows per k2f launch
#define NCOPY2 321              // ceil(S2/8)
#define TOTROWS (BB * SS)       // 65536

typedef float f32x4 __attribute__((ext_vector_type(4)));
typedef unsigned short u16;
typedef u16 u16x8 __attribute__((ext_vector_type(8)));

__device__ __forceinline__ bool is_spine(int r) {
    return (r==12)|(r==36)|(r==104)|(r==304)|(r==888)|(r==2592)|(r==7568);
}

__device__ __forceinline__ float bf2f(u16 h) {
    union { unsigned u; float f; } c; c.u = ((unsigned)h) << 16; return c.f;
}

__device__ __forceinline__ void copy_rows_nt(
    const float* __restrict__ x, float* __restrict__ out,
    long long rbase, long long rend, int lane, int wave)
{
    const f32x4* src4 = (const f32x4*)x;
    f32x4* dst4 = (f32x4*)out;
    for (int rr = wave; rr < 8; rr += 4) {
        const long long row = rbase + rr;
        if (row >= rend || row >= (long long)TOTROWS) continue;
        if (is_spine((int)(row & (SS - 1)))) continue;
        const f32x4* s = src4 + (size_t)row * 512;
        f32x4*       d = dst4 + (size_t)row * 512;
#pragma unroll
        for (int k = 0; k < 8; ++k) {
            const f32x4 v = __builtin_nontemporal_load(&s[lane + 64 * k]);
            __builtin_nontemporal_store(v, &d[lane + 64 * k]);
        }
    }
}

// ---------------------------------------------------------------------------
// cvtw: one-time gate_w f32 -> bf16 (RNE) into workspace. 4096 blocks.
// ---------------------------------------------------------------------------
__global__ __launch_bounds__(256) void cvtw(
    const float* __restrict__ gw, u16* __restrict__ gwb)
{
    const int i = (blockIdx.x * 256 + threadIdx.x) * 8;
    const f32x4 a = __builtin_nontemporal_load((const f32x4*)(gw + i));
    const f32x4 b = __builtin_nontemporal_load((const f32x4*)(gw + i + 4));
    const float v[8] = {a.x, a.y, a.z, a.w, b.x, b.y, b.z, b.w};
    u16x8 o;
#pragma unroll
    for (int k = 0; k < 8; ++k) {
        union { float f; unsigned u; } c; c.f = v[k];
        o[k] = (u16)((c.u + 0x7FFFu + ((c.u >> 16) & 1u)) >> 16);
    }
    *(u16x8*)(gwb + i) = o;
}

// ---------------------------------------------------------------------------
// k1t<WBF>: blocks [0,256) = one chain iteration's gate matvec (eager-LN
// inputs from res). Blocks >= 256 copy S1 rows of x->out (NT, spine skipped).
// ---------------------------------------------------------------------------
template<int WBF>
__global__ __launch_bounds__(256) void k1t(
    const float* __restrict__ x, int pz, long long crbase,
    const float* __restrict__ ybase, unsigned long long ybstr,
    const float* __restrict__ pbase, unsigned long long pbstr,
    const float* __restrict__ a_xz, const float* __restrict__ b_xy, const float* __restrict__ g_x,
    const float* __restrict__ a_wy, const float* __restrict__ b_wx, const float* __restrict__ g_w,
    const float* __restrict__ a_xv, const float* __restrict__ b_wv, const float* __restrict__ g_v,
    const void* __restrict__ gwv, const float* __restrict__ gate_b,
    float* __restrict__ u_out, float* __restrict__ out)
{
    __shared__ float lds[BB][DD];   // 64 KiB (unused by copy blocks)
    const int tid = threadIdx.x, lane = tid & 63, wave = tid >> 6;
    const size_t bstr_x = (size_t)SS * DD;

    // ------------------------- copy role -------------------------
    if (blockIdx.x >= NCHAIN) {
        const int cb = blockIdx.x - NCHAIN;
        copy_rows_nt(x, out, crbase + (long long)cb * 8, crbase + S1, lane, wave);
        return;
    }

    // ------------------------- chain role ------------------------
    const float* zrow = x + (size_t)pz * DD;

    // Stage v into LDS for all 8 batches.
    for (int dd = 0; dd < DD; dd += 256) {
        const int d = dd + tid;
        const float axz = a_xz[d], bxy = b_xy[d], gx  = g_x[d];
        const float awy = a_wy[d], bwx = b_wx[d], gww = g_w[d];
        const float axv = a_xv[d], bwv = b_wv[d], gv  = g_v[d];
#pragma unroll
        for (int b = 0; b < BB; ++b) {
            const float z  = zrow[(size_t)b * bstr_x + d];
            const float y  = ybase[(size_t)b * ybstr + d];
            const float xp = pbase[(size_t)b * pbstr + d];
            lds[b][d] = axv * (axz * z + bxy * y + gx)
                      + bwv * (awy * y + bwx * xp + gww) + gv;
        }
    }
    __syncthreads();

    const int d0 = blockIdx.x * 8 + wave * 2;
    const int myb = lane & 7, myc = (lane >> 3) & 1;

    float a0[8], a1[8];
#pragma unroll
    for (int b = 0; b < 8; ++b) { a0[b] = 0.f; a1[b] = 0.f; }

    // Phase A: v-half of the gate dot products.
    if constexpr (WBF) {
        const u16* gw0 = (const u16*)gwv + (size_t)d0 * TWO_D;
        const u16* gw1 = gw0 + TWO_D;
        for (int j = lane * 8; j < DD; j += 512) {
            const u16x8 w0 = *(const u16x8*)(gw0 + j);
            const u16x8 w1 = *(const u16x8*)(gw1 + j);
            float wf0[8], wf1[8];
#pragma unroll
            for (int k = 0; k < 8; ++k) { wf0[k] = bf2f(w0[k]); wf1[k] = bf2f(w1[k]); }
#pragma unroll
            for (int b = 0; b < 8; ++b) {
                const f32x4 v0 = *(const f32x4*)&lds[b][j];
                const f32x4 v1 = *(const f32x4*)&lds[b][j + 4];
                a0[b] += wf0[0]*v0.x + wf0[1]*v0.y + wf0[2]*v0.z + wf0[3]*v0.w
                       + wf0[4]*v1.x + wf0[5]*v1.y + wf0[6]*v1.z + wf0[7]*v1.w;
                a1[b] += wf1[0]*v0.x + wf1[1]*v0.y + wf1[2]*v0.z + wf1[3]*v0.w
                       + wf1[4]*v1.x + wf1[5]*v1.y + wf1[6]*v1.z + wf1[7]*v1.w;
            }
        }
    } else {
        const float* gw0 = (const float*)gwv + (size_t)d0 * TWO_D;
        const float* gw1 = gw0 + TWO_D;
        for (int j = lane * 4; j < DD; j += 256) {
            const float4 w0 = *(const float4*)(gw0 + j);
            const float4 w1 = *(const float4*)(gw1 + j);
#pragma unroll
            for (int b = 0; b < 8; ++b) {
                const float4 vv = *(const float4*)&lds[b][j];
                a0[b] += w0.x*vv.x + w0.y*vv.y + w0.z*vv.z + w0.w*vv.w;
                a1[b] += w1.x*vv.x + w1.y*vv.y + w1.z*vv.z + w1.w*vv.w;
            }
        }
    }
    const float vmine = (lane < 16) ? lds[myb][d0 + myc] : 0.f;
    __syncthreads();

    // Restage z into LDS (vectorized).
    for (int d4 = tid; d4 < 512; d4 += 256) {
#pragma unroll
        for (int b = 0; b < BB; ++b)
            ((f32x4*)&lds[b][0])[d4] = ((const f32x4*)(zrow + (size_t)b * bstr_x))[d4];
    }
    __syncthreads();

    // Phase B: z-half + gate + u write.
    if constexpr (WBF) {
        const u16* gw0 = (const u16*)gwv + (size_t)d0 * TWO_D + DD;
        const u16* gw1 = gw0 + TWO_D;
        for (int j = lane * 8; j < DD; j += 512) {
            const u16x8 w0 = *(const u16x8*)(gw0 + j);
            const u16x8 w1 = *(const u16x8*)(gw1 + j);
            float wf0[8], wf1[8];
#pragma unroll
            for (int k = 0; k < 8; ++k) { wf0[k] = bf2f(w0[k]); wf1[k] = bf2f(w1[k]); }
#pragma unroll
            for (int b = 0; b < 8; ++b) {
                const f32x4 v0 = *(const f32x4*)&lds[b][j];
                const f32x4 v1 = *(const f32x4*)&lds[b][j + 4];
                a0[b] += wf0[0]*v0.x + wf0[1]*v0.y + wf0[2]*v0.z + wf0[3]*v0.w
                       + wf0[4]*v1.x + wf0[5]*v1.y + wf0[6]*v1.z + wf0[7]*v1.w;
                a1[b] += wf1[0]*v0.x + wf1[1]*v0.y + wf1[2]*v0.z + wf1[3]*v0.w
                       + wf1[4]*v1.x + wf1[5]*v1.y + wf1[6]*v1.z + wf1[7]*v1.w;
            }
        }
    } else {
        const float* gw0 = (const float*)gwv + (size_t)d0 * TWO_D + DD;
        const float* gw1 = gw0 + TWO_D;
        for (int j = lane * 4; j < DD; j += 256) {
            const float4 w0 = *(const float4*)(gw0 + j);
            const float4 w1 = *(const float4*)(gw1 + j);
#pragma unroll
            for (int b = 0; b < 8; ++b) {
                const float4 zz = *(const float4*)&lds[b][j];
                a0[b] += w0.x*zz.x + w0.y*zz.y + w0.z*zz.z + w0.w*zz.w;
                a1[b] += w1.x*zz.x + w1.y*zz.y + w1.z*zz.z + w1.w*zz.w;
            }
        }
    }
#pragma unroll
    for (int b = 0; b < 8; ++b) {
#pragma unroll
        for (int off = 32; off >= 1; off >>= 1) {
            a0[b] += __shfl_xor(a0[b], off);
            a1[b] += __shfl_xor(a1[b], off);
        }
    }
    if (lane < 16) {
        const int d = d0 + myc;
        const float tot = myc ? a1[myb] : a0[myb];
        const float zmv = lds[myb][d];
        const float gg  = 1.f / (1.f + __expf(-(tot + gate_b[d])));
        u_out[myb * DD + d] = gg * vmine + (1.f - gg) * zmv;
    }
}

// ---------------------------------------------------------------------------
// k2f: blocks 0-7 layernorm the 8 rows of u -> res[it] AND inject into out;
// blocks >= 8 copy S2 rows of x->out (NT, spine rows skipped).
// ---------------------------------------------------------------------------
__global__ __launch_bounds__(256) void k2f(
    const float* __restrict__ x, long long crbase,
    const float* __restrict__ u, const float* __restrict__ lnw,
    const float* __restrict__ lnb, float* __restrict__ dst,
    float* __restrict__ out, int pz)
{
    const int tid = threadIdx.x, lane = tid & 63, wave = tid >> 6;

    if (blockIdx.x >= 8) {
        const int cb = blockIdx.x - 8;
        copy_rows_nt(x, out, crbase + (long long)cb * 8, crbase + S2, lane, wave);
        return;
    }

    const int b = blockIdx.x;
    const float* ub = u + b * DD;
    float vals[8];
    float s = 0.f, sq = 0.f;
#pragma unroll
    for (int i = 0; i < 8; ++i) {
        const float t = ub[tid + 256 * i];
        vals[i] = t; s += t; sq += t * t;
    }
#pragma unroll
    for (int off = 32; off >= 1; off >>= 1) {
        s  += __shfl_xor(s, off);
        sq += __shfl_xor(sq, off);
    }
    __shared__ float red[2][4];
    if (lane == 0) { red[0][wave] = s; red[1][wave] = sq; }
    __syncthreads();
    s  = red[0][0] + red[0][1] + red[0][2] + red[0][3];
    sq = red[1][0] + red[1][1] + red[1][2] + red[1][3];
    const float mean = s * (1.f / DD);
    const float var  = sq * (1.f / DD) - mean * mean;
    const float rs   = rsqrtf(var + LN_EPS);
    float* db = dst + b * DD;
    float* ob = out + (size_t)b * SS * DD + (size_t)pz * DD;
#pragma unroll
    for (int i = 0; i < 8; ++i) {
        const int d = tid + 256 * i;
        const float r = (vals[i] - mean) * rs * lnw[d] + lnb[d];
        db[d] = r;
        ob[d] = r;
    }
}

extern "C" void kernel_launch(void* const* d_in, const int* in_sizes, int n_in,
                              void* d_out, int out_size, void* d_ws, size_t ws_size,
                              hipStream_t stream)
{
    const float* x      = (const float*)d_in[0];
    const float* a_xz   = (const float*)d_in[1];
    const float* b_xy   = (const float*)d_in[2];
    const float* g_x    = (const float*)d_in[3];
    const float* a_wy   = (const float*)d_in[4];
    const float* b_wx   = (const float*)d_in[5];
    const float* g_w    = (const float*)d_in[6];
    const float* a_xv   = (const float*)d_in[7];
    const float* b_wv   = (const float*)d_in[8];
    const float* g_v    = (const float*)d_in[9];
    const float* gate_w = (const float*)d_in[10];
    const float* gate_b = (const float*)d_in[11];
    const float* ln_w   = (const float*)d_in[12];
    const float* ln_b   = (const float*)d_in[13];
    float* out = (float*)d_out;

    float* u_buf = (float*)d_ws;                 // 8*2048 f32 (pre-LN u)
    float* res   = u_buf + BB * DD;              // 7 * 8*2048 f32 LN'd rows
    const size_t head = (size_t)(BB * DD + 7 * BB * DD) * 4;   // 512 KiB
    u16* gwb = (u16*)((char*)d_ws + head);       // bf16 gate_w (16 MiB)
    const size_t need = head + (size_t)DD * TWO_D * 2;
    const bool usebf = (ws_size >= need);

    static const int PZ[7] = {12, 36, 104, 304, 888, 2592, 7568};
    static const int PY[7] = {4, 12, 36, 104, 304, 888, 2592};
    static const int PX[7] = {2, 4, 12, 36, 104, 304, 888};

    if (usebf)
        hipLaunchKernelGGL(cvtw, dim3((DD * TWO_D) / (256 * 8)), dim3(256), 0, stream,
                           gate_w, gwb);

    // Copy-row layout: k1t launches own rows [0, 7*S1); k2f launches own
    // rows [7*S1, 65536) in S2 slices (last clamped in-kernel).
    long long c1 = 0, c2 = (long long)7 * S1;

    for (int it = 0; it < 7; ++it) {
        const float* ybase; unsigned long long ybstr;
        const float* pbase; unsigned long long pbstr;
        if (it == 0) { ybase = x + (size_t)PY[0] * DD; ybstr = (size_t)SS * DD; }
        else         { ybase = res + (size_t)(it - 1) * BB * DD; ybstr = DD; }
        if (it <= 1) { pbase = x + (size_t)PX[it] * DD; pbstr = (size_t)SS * DD; }
        else         { pbase = res + (size_t)(it - 2) * BB * DD; pbstr = DD; }

        if (usebf)
            hipLaunchKernelGGL((k1t<1>), dim3(NCHAIN + NCOPY1), dim3(256), 0, stream,
                               x, PZ[it], c1, ybase, ybstr, pbase, pbstr,
                               a_xz, b_xy, g_x, a_wy, b_wx, g_w, a_xv, b_wv, g_v,
                               (const void*)gwb, gate_b, u_buf, out);
        else
            hipLaunchKernelGGL((k1t<0>), dim3(NCHAIN + NCOPY1), dim3(256), 0, stream,
                               x, PZ[it], c1, ybase, ybstr, pbase, pbstr,
                               a_xz, b_xy, g_x, a_wy, b_wx, g_w, a_xv, b_wv, g_v,
                               (const void*)gate_w, gate_b, u_buf, out);
        c1 += S1;

        hipLaunchKernelGGL(k2f, dim3(8 + NCOPY2), dim3(256), 0, stream,
                           x, c2, u_buf, ln_w, ln_b,
                           res + (size_t)it * BB * DD, out, PZ[it]);
        c2 += S2;
    }
}

// Round 15
// 251.562 us; speedup vs baseline: 1.1403x; 1.1403x over previous
//
#include <hip/hip_runtime.h>

#define DD 2048
#define SS 8192
#define BB 8
#define TWO_D 4096
#define LN_EPS 1e-5f
#define NCHAIN 256              // chain blocks (8 output cols each)
#define SLICE  9364             // copy rows per k1 launch (7*9364 >= 65536)
#define NCOPY  1171             // copy blocks per launch (8 rows each)
#define TOTROWS (BB * SS)       // 65536

typedef float f32x4 __attribute__((ext_vector_type(4)));
typedef unsigned short u16;
typedef u16 u16x4 __attribute__((ext_vector_type(4)));
typedef u16 u16x8 __attribute__((ext_vector_type(8)));

__device__ __forceinline__ bool is_spine(int r) {
    return (r==12)|(r==36)|(r==104)|(r==304)|(r==888)|(r==2592)|(r==7568);
}

__device__ __forceinline__ float bf2f(u16 h) {
    union { unsigned u; float f; } c; c.u = ((unsigned)h) << 16; return c.f;
}

__device__ __forceinline__ u16 f2bf(float f) {
    union { float f; unsigned u; } c; c.f = f;
    return (u16)((c.u + 0x7FFFu + ((c.u >> 16) & 1u)) >> 16);
}

// ---------------------------------------------------------------------------
// k1t<MODE>: blocks [0,256) = one chain iteration's gate matvec (eager-LN
// inputs from res). Blocks >= 256 copy SLICE rows of x->out (NT, spine
// rows skipped; k2_ln owns those).
//   MODE 0: weights f32; additionally EMIT bf16 copies to gwb (launch 0).
//   MODE 1: weights bf16 from gwb (launches 1-6).
//   MODE 2: weights f32, no emit (fallback when ws too small).
// ---------------------------------------------------------------------------
template<int MODE>
__global__ __launch_bounds__(256) void k1t(
    const float* __restrict__ x, int pz, long long crbase,
    const float* __restrict__ ybase, unsigned long long ybstr,
    const float* __restrict__ pbase, unsigned long long pbstr,
    const float* __restrict__ a_xz, const float* __restrict__ b_xy, const float* __restrict__ g_x,
    const float* __restrict__ a_wy, const float* __restrict__ b_wx, const float* __restrict__ g_w,
    const float* __restrict__ a_xv, const float* __restrict__ b_wv, const float* __restrict__ g_v,
    const float* __restrict__ gate_w, u16* __restrict__ gwb,
    const float* __restrict__ gate_b,
    float* __restrict__ u_out, float* __restrict__ out)
{
    __shared__ float lds[BB][DD];   // 64 KiB (unused by copy blocks)
    const int tid = threadIdx.x, lane = tid & 63, wave = tid >> 6;
    const size_t bstr_x = (size_t)SS * DD;

    // ------------------------- copy role -------------------------
    if (blockIdx.x >= NCHAIN) {
        const int cb = blockIdx.x - NCHAIN;
        const long long rbase = crbase + (long long)cb * 8;
        const f32x4* src4 = (const f32x4*)x;
        f32x4* dst4 = (f32x4*)out;
        for (int rr = wave; rr < 8; rr += 4) {
            const long long row = rbase + rr;
            if (row >= (long long)TOTROWS) continue;
            if (is_spine((int)(row & (SS - 1)))) continue;
            const f32x4* s = src4 + (size_t)row * 512;
            f32x4*       d = dst4 + (size_t)row * 512;
#pragma unroll
            for (int k = 0; k < 8; ++k) {
                const f32x4 v = __builtin_nontemporal_load(&s[lane + 64 * k]);
                __builtin_nontemporal_store(v, &d[lane + 64 * k]);
            }
        }
        return;
    }

    // ------------------------- chain role ------------------------
    const float* zrow = x + (size_t)pz * DD;

    // Stage v into LDS for all 8 batches.
    for (int dd = 0; dd < DD; dd += 256) {
        const int d = dd + tid;
        const float axz = a_xz[d], bxy = b_xy[d], gx  = g_x[d];
        const float awy = a_wy[d], bwx = b_wx[d], gww = g_w[d];
        const float axv = a_xv[d], bwv = b_wv[d], gv  = g_v[d];
#pragma unroll
        for (int b = 0; b < BB; ++b) {
            const float z  = zrow[(size_t)b * bstr_x + d];
            const float y  = ybase[(size_t)b * ybstr + d];
            const float xp = pbase[(size_t)b * pbstr + d];
            lds[b][d] = axv * (axz * z + bxy * y + gx)
                      + bwv * (awy * y + bwx * xp + gww) + gv;
        }
    }
    __syncthreads();

    const int d0 = blockIdx.x * 8 + wave * 2;
    const int myb = lane & 7, myc = (lane >> 3) & 1;

    float a0[8], a1[8];
#pragma unroll
    for (int b = 0; b < 8; ++b) { a0[b] = 0.f; a1[b] = 0.f; }

    // Phase A: v-half of the gate dot products.
    if constexpr (MODE == 1) {
        const u16* gw0 = gwb + (size_t)d0 * TWO_D;
        const u16* gw1 = gw0 + TWO_D;
        for (int j = lane * 8; j < DD; j += 512) {
            const u16x8 w0 = *(const u16x8*)(gw0 + j);
            const u16x8 w1 = *(const u16x8*)(gw1 + j);
            float wf0[8], wf1[8];
#pragma unroll
            for (int k = 0; k < 8; ++k) { wf0[k] = bf2f(w0[k]); wf1[k] = bf2f(w1[k]); }
#pragma unroll
            for (int b = 0; b < 8; ++b) {
                const f32x4 v0 = *(const f32x4*)&lds[b][j];
                const f32x4 v1 = *(const f32x4*)&lds[b][j + 4];
                a0[b] += wf0[0]*v0.x + wf0[1]*v0.y + wf0[2]*v0.z + wf0[3]*v0.w
                       + wf0[4]*v1.x + wf0[5]*v1.y + wf0[6]*v1.z + wf0[7]*v1.w;
                a1[b] += wf1[0]*v0.x + wf1[1]*v0.y + wf1[2]*v0.z + wf1[3]*v0.w
                       + wf1[4]*v1.x + wf1[5]*v1.y + wf1[6]*v1.z + wf1[7]*v1.w;
            }
        }
    } else {
        const float* gw0 = gate_w + (size_t)d0 * TWO_D;
        const float* gw1 = gw0 + TWO_D;
        for (int j = lane * 4; j < DD; j += 256) {
            const float4 w0 = *(const float4*)(gw0 + j);
            const float4 w1 = *(const float4*)(gw1 + j);
            if constexpr (MODE == 0) {
                u16x4 o0, o1;
                o0[0]=f2bf(w0.x); o0[1]=f2bf(w0.y); o0[2]=f2bf(w0.z); o0[3]=f2bf(w0.w);
                o1[0]=f2bf(w1.x); o1[1]=f2bf(w1.y); o1[2]=f2bf(w1.z); o1[3]=f2bf(w1.w);
                *(u16x4*)(gwb + (size_t)d0 * TWO_D + j) = o0;
                *(u16x4*)(gwb + (size_t)(d0 + 1) * TWO_D + j) = o1;
            }
#pragma unroll
            for (int b = 0; b < 8; ++b) {
                const float4 vv = *(const float4*)&lds[b][j];
                a0[b] += w0.x*vv.x + w0.y*vv.y + w0.z*vv.z + w0.w*vv.w;
                a1[b] += w1.x*vv.x + w1.y*vv.y + w1.z*vv.z + w1.w*vv.w;
            }
        }
    }
    const float vmine = (lane < 16) ? lds[myb][d0 + myc] : 0.f;
    __syncthreads();

    // Restage z into LDS (vectorized).
    for (int d4 = tid; d4 < 512; d4 += 256) {
#pragma unroll
        for (int b = 0; b < BB; ++b)
            ((f32x4*)&lds[b][0])[d4] = ((const f32x4*)(zrow + (size_t)b * bstr_x))[d4];
    }
    __syncthreads();

    // Phase B: z-half + gate + u write.
    if constexpr (MODE == 1) {
        const u16* gw0 = gwb + (size_t)d0 * TWO_D + DD;
        const u16* gw1 = gw0 + TWO_D;
        for (int j = lane * 8; j < DD; j += 512) {
            const u16x8 w0 = *(const u16x8*)(gw0 + j);
            const u16x8 w1 = *(const u16x8*)(gw1 + j);
            float wf0[8], wf1[8];
#pragma unroll
            for (int k = 0; k < 8; ++k) { wf0[k] = bf2f(w0[k]); wf1[k] = bf2f(w1[k]); }
#pragma unroll
            for (int b = 0; b < 8; ++b) {
                const f32x4 v0 = *(const f32x4*)&lds[b][j];
                const f32x4 v1 = *(const f32x4*)&lds[b][j + 4];
                a0[b] += wf0[0]*v0.x + wf0[1]*v0.y + wf0[2]*v0.z + wf0[3]*v0.w
                       + wf0[4]*v1.x + wf0[5]*v1.y + wf0[6]*v1.z + wf0[7]*v1.w;
                a1[b] += wf1[0]*v0.x + wf1[1]*v0.y + wf1[2]*v0.z + wf1[3]*v0.w
                       + wf1[4]*v1.x + wf1[5]*v1.y + wf1[6]*v1.z + wf1[7]*v1.w;
            }
        }
    } else {
        const float* gw0 = gate_w + (size_t)d0 * TWO_D + DD;
        const float* gw1 = gw0 + TWO_D;
        for (int j = lane * 4; j < DD; j += 256) {
            const float4 w0 = *(const float4*)(gw0 + j);
            const float4 w1 = *(const float4*)(gw1 + j);
            if constexpr (MODE == 0) {
                u16x4 o0, o1;
                o0[0]=f2bf(w0.x); o0[1]=f2bf(w0.y); o0[2]=f2bf(w0.z); o0[3]=f2bf(w0.w);
                o1[0]=f2bf(w1.x); o1[1]=f2bf(w1.y); o1[2]=f2bf(w1.z); o1[3]=f2bf(w1.w);
                *(u16x4*)(gwb + (size_t)d0 * TWO_D + DD + j) = o0;
                *(u16x4*)(gwb + (size_t)(d0 + 1) * TWO_D + DD + j) = o1;
            }
#pragma unroll
            for (int b = 0; b < 8; ++b) {
                const float4 zz = *(const float4*)&lds[b][j];
                a0[b] += w0.x*zz.x + w0.y*zz.y + w0.z*zz.z + w0.w*zz.w;
                a1[b] += w1.x*zz.x + w1.y*zz.y + w1.z*zz.z + w1.w*zz.w;
            }
        }
    }
#pragma unroll
    for (int b = 0; b < 8; ++b) {
#pragma unroll
        for (int off = 32; off >= 1; off >>= 1) {
            a0[b] += __shfl_xor(a0[b], off);
            a1[b] += __shfl_xor(a1[b], off);
        }
    }
    if (lane < 16) {
        const int d = d0 + myc;
        const float tot = myc ? a1[myb] : a0[myb];
        const float zmv = lds[myb][d];
        const float gg  = 1.f / (1.f + __expf(-(tot + gate_b[d])));
        u_out[myb * DD + d] = gg * vmine + (1.f - gg) * zmv;
    }
}

// ---------------------------------------------------------------------------
// k2_ln: layernorm the 8 rows of u; write to res[it] AND inject into out.
// ---------------------------------------------------------------------------
__global__ __launch_bounds__(256) void k2_ln(
    const float* __restrict__ u, const float* __restrict__ lnw,
    const float* __restrict__ lnb, float* __restrict__ dst,
    float* __restrict__ out, int pz)
{
    const int b = blockIdx.x, tid = threadIdx.x;
    const float* ub = u + b * DD;
    float vals[8];
    float s = 0.f, sq = 0.f;
#pragma unroll
    for (int i = 0; i < 8; ++i) {
        const float t = ub[tid + 256 * i];
        vals[i] = t; s += t; sq += t * t;
    }
    const int wave = tid >> 6, lane = tid & 63;
#pragma unroll
    for (int off = 32; off >= 1; off >>= 1) {
        s  += __shfl_xor(s, off);
        sq += __shfl_xor(sq, off);
    }
    __shared__ float red[2][4];
    if (lane == 0) { red[0][wave] = s; red[1][wave] = sq; }
    __syncthreads();
    s  = red[0][0] + red[0][1] + red[0][2] + red[0][3];
    sq = red[1][0] + red[1][1] + red[1][2] + red[1][3];
    const float mean = s * (1.f / DD);
    const float var  = sq * (1.f / DD) - mean * mean;
    const float rs   = rsqrtf(var + LN_EPS);
    float* db = dst + b * DD;
    float* ob = out + (size_t)b * SS * DD + (size_t)pz * DD;
#pragma unroll
    for (int i = 0; i < 8; ++i) {
        const int d = tid + 256 * i;
        const float r = (vals[i] - mean) * rs * lnw[d] + lnb[d];
        db[d] = r;
        ob[d] = r;
    }
}

extern "C" void kernel_launch(void* const* d_in, const int* in_sizes, int n_in,
                              void* d_out, int out_size, void* d_ws, size_t ws_size,
                              hipStream_t stream)
{
    const float* x      = (const float*)d_in[0];
    const float* a_xz   = (const float*)d_in[1];
    const float* b_xy   = (const float*)d_in[2];
    const float* g_x    = (const float*)d_in[3];
    const float* a_wy   = (const float*)d_in[4];
    const float* b_wx   = (const float*)d_in[5];
    const float* g_w    = (const float*)d_in[6];
    const float* a_xv   = (const float*)d_in[7];
    const float* b_wv   = (const float*)d_in[8];
    const float* g_v    = (const float*)d_in[9];
    const float* gate_w = (const float*)d_in[10];
    const float* gate_b = (const float*)d_in[11];
    const float* ln_w   = (const float*)d_in[12];
    const float* ln_b   = (const float*)d_in[13];
    float* out = (float*)d_out;

    float* u_buf = (float*)d_ws;                 // 8*2048 f32 (pre-LN u)
    float* res   = u_buf + BB * DD;              // 7 * 8*2048 f32 LN'd rows
    const size_t head = (size_t)(BB * DD + 7 * BB * DD) * 4;   // 512 KiB
    u16* gwb = (u16*)((char*)d_ws + head);       // bf16 gate_w (16 MiB)
    const size_t need = head + (size_t)DD * TWO_D * 2;
    const bool usebf = (ws_size >= need);

    static const int PZ[7] = {12, 36, 104, 304, 888, 2592, 7568};
    static const int PY[7] = {4, 12, 36, 104, 304, 888, 2592};
    static const int PX[7] = {2, 4, 12, 36, 104, 304, 888};

    long long c1 = 0;
    for (int it = 0; it < 7; ++it) {
        const float* ybase; unsigned long long ybstr;
        const float* pbase; unsigned long long pbstr;
        if (it == 0) { ybase = x + (size_t)PY[0] * DD; ybstr = (size_t)SS * DD; }
        else         { ybase = res + (size_t)(it - 1) * BB * DD; ybstr = DD; }
        if (it <= 1) { pbase = x + (size_t)PX[it] * DD; pbstr = (size_t)SS * DD; }
        else         { pbase = res + (size_t)(it - 2) * BB * DD; pbstr = DD; }

        if (!usebf) {
            hipLaunchKernelGGL((k1t<2>), dim3(NCHAIN + NCOPY), dim3(256), 0, stream,
                               x, PZ[it], c1, ybase, ybstr, pbase, pbstr,
                               a_xz, b_xy, g_x, a_wy, b_wx, g_w, a_xv, b_wv, g_v,
                               gate_w, (u16*)nullptr, gate_b, u_buf, out);
        } else if (it == 0) {
            hipLaunchKernelGGL((k1t<0>), dim3(NCHAIN + NCOPY), dim3(256), 0, stream,
                               x, PZ[it], c1, ybase, ybstr, pbase, pbstr,
                               a_xz, b_xy, g_x, a_wy, b_wx, g_w, a_xv, b_wv, g_v,
                               gate_w, gwb, gate_b, u_buf, out);
        } else {
            hipLaunchKernelGGL((k1t<1>), dim3(NCHAIN + NCOPY), dim3(256), 0, stream,
                               x, PZ[it], c1, ybase, ybstr, pbase, pbstr,
                               a_xz, b_xy, g_x, a_wy, b_wx, g_w, a_xv, b_wv, g_v,
                               gate_w, gwb, gate_b, u_buf, out);
        }
        c1 += SLICE;

        hipLaunchKernelGGL(k2_ln, dim3(BB), dim3(256), 0, stream,
                           u_buf, ln_w, ln_b, res + (size_t)it * BB * DD,
                           out, PZ[it]);
    }
}